// Round 1
// baseline (1065.736 us; speedup 1.0000x reference)
//
#include <hip/hip_runtime.h>
#include <hip/hip_bf16.h>

#define N_NODESC 100000
#define N_EDGESC 1000000
#define N_QUERYC 100000

// ---------- dual-dtype load helper (flag: 1 = inputs are bf16, 0 = f32) ----------
__device__ __forceinline__ float ldf(const void* p, int i, int isbf) {
  return isbf ? __bfloat162float(((const __hip_bfloat16*)p)[i])
              : ((const float*)p)[i];
}

// ---------- 0: sniff input dtype ----------
__global__ void k_sniff(const void* x, int* flag) {
  __shared__ int cnt;
  int t = threadIdx.x;
  if (t == 0) cnt = 0;
  __syncthreads();
  const unsigned short* h = (const unsigned short*)x;
  int local = 0;
  for (int i = t; i < 4096; i += 256) {
    int e = (h[i] >> 7) & 0xFF;          // bf16 exponent field
    if (e >= 107 && e <= 133) local++;   // |x| roughly in [1e-6, 128)
  }
  atomicAdd(&cnt, local);
  __syncthreads();
  if (t == 0) *flag = (cnt >= 3482) ? 1 : 0;  // >=85% plausible => bf16
}

// ---------- 1: histogram of dst ----------
__global__ void k_hist(const int* __restrict__ dst, int* __restrict__ cnt, int ne) {
  int e = blockIdx.x * 256 + threadIdx.x;
  if (e < ne) atomicAdd(&cnt[dst[e]], 1);
}

// ---------- 2a: per-chunk exclusive scan (1024 elements/block) ----------
__global__ void k_scan1(const int* __restrict__ cnt, int* __restrict__ off,
                        int* __restrict__ partials, int n) {
  __shared__ int s[1024];
  int t = threadIdx.x;
  int idx = blockIdx.x * 1024 + t;
  int v = (idx < n) ? cnt[idx] : 0;
  s[t] = v;
  __syncthreads();
  for (int d = 1; d < 1024; d <<= 1) {
    int tmp = (t >= d) ? s[t - d] : 0;
    __syncthreads();
    s[t] += tmp;
    __syncthreads();
  }
  if (idx < n) off[idx] = s[t] - v;            // local exclusive
  if (t == 1023) partials[blockIdx.x] = s[1023];
}

// ---------- 2b: scan the 98 chunk totals ----------
__global__ void k_scan2(const int* __restrict__ partials, int* __restrict__ pref,
                        int* __restrict__ off, int nb, int npos) {
  __shared__ int s[128];
  int t = threadIdx.x;
  int v = (t < nb) ? partials[t] : 0;
  s[t] = v;
  __syncthreads();
  for (int d = 1; d < 128; d <<= 1) {
    int tmp = (t >= d) ? s[t - d] : 0;
    __syncthreads();
    s[t] += tmp;
    __syncthreads();
  }
  if (t < nb) pref[t] = s[t] - v;
  if (t == 127) off[npos] = s[127];            // offsets[N_NODES] = total
}

// ---------- 2c: apply chunk prefixes, init cursor ----------
__global__ void k_scan3(int* __restrict__ off, const int* __restrict__ pref,
                        int* __restrict__ cursor, int n) {
  int i = blockIdx.x * 256 + threadIdx.x;
  if (i < n) {
    int o = off[i] + pref[i >> 10];
    off[i] = o;
    cursor[i] = o;
  }
}

// ---------- 3: bucket fill (store negated norms: m = -norm) ----------
__global__ void k_fill(const int* __restrict__ ei,
                       const void* nr, const void* ni, const void* nj, const void* nk,
                       const int* __restrict__ flagp, int* __restrict__ cursor,
                       int* __restrict__ srcS, float* __restrict__ mr,
                       float* __restrict__ mi, float* __restrict__ mj,
                       float* __restrict__ mk, int ne) {
  int isbf = *flagp;
  int e = blockIdx.x * 256 + threadIdx.x;
  if (e >= ne) return;
  int s = ei[e];
  int d = ei[ne + e];
  int pos = atomicAdd(&cursor[d], 1);
  srcS[pos] = s;
  mr[pos] = -ldf(nr, e, isbf);
  mi[pos] = -ldf(ni, e, isbf);
  mj[pos] = -ldf(nj, e, isbf);
  mk[pos] = -ldf(nk, e, isbf);
}

// ---------- 4: per-node quaternion aggregation (one wave per node) ----------
// T = sum_{edges into node} (-n_e) (x) X[src_e]   (Hamilton product)
__global__ __launch_bounds__(256) void k_agg(
    const void* X0, const void* X1, const void* X2, const void* X3,
    int stride, const int* __restrict__ flagp, int use_flag,
    const int* __restrict__ off, const int* __restrict__ srcS,
    const float* __restrict__ mr, const float* __restrict__ mi,
    const float* __restrict__ mj, const float* __restrict__ mk,
    float* __restrict__ T, int nnodes) {
  int isbf = use_flag ? *flagp : 0;
  int lane = threadIdx.x & 63;
  int node = blockIdx.x * 4 + (threadIdx.x >> 6);
  if (node >= nnodes) return;
  int rs = off[node], re = off[node + 1];
  float tr = 0.f, ti = 0.f, tj = 0.f, tk = 0.f;
  for (int e = rs; e < re; ++e) {
    int s = srcS[e];
    float ar = mr[e], ai = mi[e], aj = mj[e], ak = mk[e];
    int base = s * stride + lane;
    float gr = ldf(X0, base, isbf);
    float gi = ldf(X1, base, isbf);
    float gj = ldf(X2, base, isbf);
    float gk = ldf(X3, base, isbf);
    tr += ar * gr - ai * gi - aj * gj - ak * gk;
    ti += ar * gi + ai * gr + aj * gk - ak * gj;
    tj += ar * gj - ai * gk + aj * gr + ak * gi;
    tk += ar * gk + ai * gj - aj * gi + ak * gr;
  }
  int o = node * 256 + lane;
  T[o] = tr;
  T[o + 64] = ti;
  T[o + 128] = tj;
  T[o + 192] = tk;
}

// ---------- 5: build effective 256x256 weight (quaternion structure) ----------
// Weff[a*64+k, c*64+h] = sign(a,c) * W[a^c][k][h];  bcat = b flat (4,64)
__global__ void k_weff(const void* W, const void* b, const int* __restrict__ flagp,
                       float* __restrict__ Weff, float* __restrict__ bcat) {
  int isbf = *flagp;
  int t = blockIdx.x * 256 + threadIdx.x;  // 0..65535
  int row = t >> 8;    // a*64+k
  int col = t & 255;   // c*64+h
  int a = row >> 6, k = row & 63, c = col >> 6, h = col & 63;
  int w = a ^ c;
  float sgn = ((0x3950 >> (a * 4 + c)) & 1) ? -1.f : 1.f;
  Weff[t] = sgn * ldf(W, w * 4096 + k * 64 + h, isbf);
  if (t < 256) bcat[t] = ldf(b, t, isbf);
}

// ---------- 6: GEMM (M x 256) @ (256 x 256) + bias, ReLU ----------
// 128x128 block tile, 8x8 per thread, f32
__global__ __launch_bounds__(256) void k_gemm_relu(
    const float* __restrict__ A, const float* __restrict__ B,
    const float* __restrict__ bias, float* __restrict__ C, int M) {
  __shared__ float As[8][128];
  __shared__ float Bs[8][128];
  int t = threadIdx.x;
  int n0 = blockIdx.x * 128;
  int j0 = blockIdx.y * 128;
  int tx = t & 15, ty = t >> 4;

  float acc[8][8];
#pragma unroll
  for (int i = 0; i < 8; i++)
#pragma unroll
    for (int j = 0; j < 8; j++) acc[i][j] = 0.f;

  int ar = t >> 1, akb = (t & 1) * 4;   // A: row, k-subblock
  int arow = n0 + ar;
  bool avalid = arow < M;
  int bkk = t >> 5, bjb = (t & 31) * 4; // B: k-row, col-subblock

  for (int k0 = 0; k0 < 256; k0 += 8) {
    float4 av = make_float4(0.f, 0.f, 0.f, 0.f);
    if (avalid) av = *(const float4*)&A[arow * 256 + k0 + akb];
    float4 bv = *(const float4*)&B[(k0 + bkk) * 256 + j0 + bjb];
    __syncthreads();
    As[akb + 0][ar] = av.x;
    As[akb + 1][ar] = av.y;
    As[akb + 2][ar] = av.z;
    As[akb + 3][ar] = av.w;
    *(float4*)&Bs[bkk][bjb] = bv;
    __syncthreads();
#pragma unroll
    for (int kk = 0; kk < 8; kk++) {
      float a_[8], b_[8];
      *(float4*)&a_[0] = *(const float4*)&As[kk][ty * 8];
      *(float4*)&a_[4] = *(const float4*)&As[kk][ty * 8 + 4];
      *(float4*)&b_[0] = *(const float4*)&Bs[kk][tx * 8];
      *(float4*)&b_[4] = *(const float4*)&Bs[kk][tx * 8 + 4];
#pragma unroll
      for (int i = 0; i < 8; i++)
#pragma unroll
        for (int j = 0; j < 8; j++) acc[i][j] += a_[i] * b_[j];
    }
  }

  float bb[8];
  *(float4*)&bb[0] = *(const float4*)&bias[j0 + tx * 8];
  *(float4*)&bb[4] = *(const float4*)&bias[j0 + tx * 8 + 4];
#pragma unroll
  for (int i = 0; i < 8; i++) {
    int row = n0 + ty * 8 + i;
    if (row < M) {
      float4 o1, o2;
      o1.x = fmaxf(acc[i][0] + bb[0], 0.f);
      o1.y = fmaxf(acc[i][1] + bb[1], 0.f);
      o1.z = fmaxf(acc[i][2] + bb[2], 0.f);
      o1.w = fmaxf(acc[i][3] + bb[3], 0.f);
      o2.x = fmaxf(acc[i][4] + bb[4], 0.f);
      o2.y = fmaxf(acc[i][5] + bb[5], 0.f);
      o2.z = fmaxf(acc[i][6] + bb[6], 0.f);
      o2.w = fmaxf(acc[i][7] + bb[7], 0.f);
      *(float4*)&C[row * 256 + j0 + tx * 8] = o1;
      *(float4*)&C[row * 256 + j0 + tx * 8 + 4] = o2;
    }
  }
}

// ---------- 7: per-node partial dots with Cw (one wave per node) ----------
// P[n*4+0]=endpoint0/label0, +1=endpoint1/label0, +2=endpoint0/label1, +3=endpoint1/label1
__global__ __launch_bounds__(256) void k_pdots(const float* __restrict__ X,
                                               const void* Cw,
                                               const int* __restrict__ flagp,
                                               float* __restrict__ P, int nnodes) {
  int isbf = *flagp;
  int lane = threadIdx.x & 63;
  int node = blockIdx.x * 4 + (threadIdx.x >> 6);
  if (node >= nnodes) return;
  float p00 = 0.f, p01 = 0.f, p10 = 0.f, p11 = 0.f;
#pragma unroll
  for (int c = 0; c < 4; c++) {
    float x = X[node * 256 + c * 64 + lane];
    p00 += x * ldf(Cw, c * 128 + lane, isbf);
    p01 += x * ldf(Cw, c * 128 + 64 + lane, isbf);
    p10 += x * ldf(Cw, 512 + c * 128 + lane, isbf);
    p11 += x * ldf(Cw, 512 + c * 128 + 64 + lane, isbf);
  }
  for (int d = 32; d > 0; d >>= 1) {
    p00 += __shfl_down(p00, d);
    p01 += __shfl_down(p01, d);
    p10 += __shfl_down(p10, d);
    p11 += __shfl_down(p11, d);
  }
  if (lane == 0) {
    float4 v = make_float4(p00, p01, p10, p11);
    *(float4*)&P[node * 4] = v;
  }
}

// ---------- 8: per-query logits + log_softmax ----------
__global__ void k_query(const int* __restrict__ qe, const float* __restrict__ P,
                        const void* Cb, const int* __restrict__ flagp,
                        void* out, int nq) {
  int isbf = *flagp;
  int q = blockIdx.x * 256 + threadIdx.x;
  if (q >= nq) return;
  int q0 = qe[q * 2], q1 = qe[q * 2 + 1];
  float l0 = P[q0 * 4 + 0] + P[q1 * 4 + 1] + ldf(Cb, 0, isbf);
  float l1 = P[q0 * 4 + 2] + P[q1 * 4 + 3] + ldf(Cb, 1, isbf);
  float m = fmaxf(l0, l1);
  float lse = m + logf(expf(l0 - m) + expf(l1 - m));
  float o0 = l0 - lse, o1 = l1 - lse;
  if (isbf) {
    __hip_bfloat16* o = (__hip_bfloat16*)out;
    o[q * 2] = __float2bfloat16(o0);
    o[q * 2 + 1] = __float2bfloat16(o1);
  } else {
    float* o = (float*)out;
    o[q * 2] = o0;
    o[q * 2 + 1] = o1;
  }
}

extern "C" void kernel_launch(void* const* d_in, const int* in_sizes, int n_in,
                              void* d_out, int out_size, void* d_ws, size_t ws_size,
                              hipStream_t stream) {
  const int N = N_NODESC, NE = N_EDGESC, NQ = N_QUERYC;

  // ---- workspace layout ----
  char* w = (char*)d_ws;
  auto alloc = [&](size_t bytes) -> void* {
    void* p = (void*)w;
    w += (bytes + 255) & ~(size_t)255;
    return p;
  };
  int* flag     = (int*)alloc(4);
  int* offsets  = (int*)alloc((size_t)(N + 1) * 4);
  int* cursor   = (int*)alloc((size_t)N * 4);
  int* partials = (int*)alloc(128 * 4);
  int* pref     = (int*)alloc(128 * 4);
  int* srcS     = (int*)alloc((size_t)NE * 4);
  float* mr     = (float*)alloc((size_t)NE * 4);
  float* mi     = (float*)alloc((size_t)NE * 4);
  float* mj     = (float*)alloc((size_t)NE * 4);
  float* mk     = (float*)alloc((size_t)NE * 4);
  float* Tbuf   = (float*)alloc((size_t)N * 256 * 4);
  float* Xbuf   = (float*)alloc((size_t)N * 256 * 4);
  float* Weff   = (float*)alloc(256 * 256 * 4);
  float* bcat   = (float*)alloc(256 * 4);
  float* P      = (float*)alloc((size_t)N * 4 * 4);
  (void)ws_size; (void)n_in; (void)in_sizes; (void)out_size;

  const int* ei = (const int*)d_in[8];

  // dtype sniff
  k_sniff<<<1, 256, 0, stream>>>(d_in[0], flag);

  // CSR build (shared by both layers)
  hipMemsetAsync(cursor, 0, (size_t)N * 4, stream);
  k_hist<<<(NE + 255) / 256, 256, 0, stream>>>(ei + NE, cursor, NE);
  k_scan1<<<(N + 1023) / 1024, 1024, 0, stream>>>(cursor, offsets, partials, N);
  k_scan2<<<1, 128, 0, stream>>>(partials, pref, offsets, (N + 1023) / 1024, N);
  k_scan3<<<(N + 255) / 256, 256, 0, stream>>>(offsets, pref, cursor, N);
  k_fill<<<(NE + 255) / 256, 256, 0, stream>>>(ei, d_in[4], d_in[5], d_in[6], d_in[7],
                                               flag, cursor, srcS, mr, mi, mj, mk, NE);

  dim3 gemm_grid((N + 127) / 128, 2);

  // layer 1
  k_agg<<<(N + 3) / 4, 256, 0, stream>>>(d_in[0], d_in[1], d_in[2], d_in[3], 64,
                                         flag, 1, offsets, srcS, mr, mi, mj, mk, Tbuf, N);
  k_weff<<<256, 256, 0, stream>>>(d_in[10], d_in[11], flag, Weff, bcat);
  k_gemm_relu<<<gemm_grid, 256, 0, stream>>>(Tbuf, Weff, bcat, Xbuf, N);

  // layer 2
  k_agg<<<(N + 3) / 4, 256, 0, stream>>>(Xbuf, Xbuf + 64, Xbuf + 128, Xbuf + 192, 256,
                                         flag, 0, offsets, srcS, mr, mi, mj, mk, Tbuf, N);
  k_weff<<<256, 256, 0, stream>>>(d_in[12], d_in[13], flag, Weff, bcat);
  k_gemm_relu<<<gemm_grid, 256, 0, stream>>>(Tbuf, Weff, bcat, Xbuf, N);

  // readout
  k_pdots<<<(N + 3) / 4, 256, 0, stream>>>(Xbuf, d_in[14], flag, P, N);
  k_query<<<(NQ + 255) / 256, 256, 0, stream>>>((const int*)d_in[9], P, d_in[15],
                                                flag, d_out, NQ);
}

// Round 2
// 788.870 us; speedup vs baseline: 1.3510x; 1.3510x over previous
//
#include <hip/hip_runtime.h>
#include <hip/hip_bf16.h>

#define N_NODESC 100000
#define N_EDGESC 1000000
#define N_QUERYC 100000

typedef short short8 __attribute__((ext_vector_type(8)));
typedef float f32x4 __attribute__((ext_vector_type(4)));

// ---------- dual-dtype load helper (flag: 1 = inputs are bf16, 0 = f32) ----------
__device__ __forceinline__ float ldf(const void* p, int i, int isbf) {
  return isbf ? __bfloat162float(((const __hip_bfloat16*)p)[i])
              : ((const float*)p)[i];
}
__device__ __forceinline__ unsigned short f2b(float x) {
  __hip_bfloat16 h = __float2bfloat16(x);
  return *(unsigned short*)&h;
}
__device__ __forceinline__ float b2f(unsigned int u) {
  return __uint_as_float(u << 16);
}

// ---------- 0: sniff input dtype ----------
__global__ void k_sniff(const void* x, int* flag) {
  __shared__ int cnt;
  int t = threadIdx.x;
  if (t == 0) cnt = 0;
  __syncthreads();
  const unsigned short* h = (const unsigned short*)x;
  int local = 0;
  for (int i = t; i < 4096; i += 256) {
    int e = (h[i] >> 7) & 0xFF;
    if (e >= 107 && e <= 133) local++;
  }
  atomicAdd(&cnt, local);
  __syncthreads();
  if (t == 0) *flag = (cnt >= 3482) ? 1 : 0;
}

// ---------- 1: histogram of dst ----------
__global__ void k_hist(const int* __restrict__ dst, int* __restrict__ cnt, int ne) {
  int e = blockIdx.x * 256 + threadIdx.x;
  if (e < ne) atomicAdd(&cnt[dst[e]], 1);
}

// ---------- 2a: per-chunk exclusive scan ----------
__global__ void k_scan1(const int* __restrict__ cnt, int* __restrict__ off,
                        int* __restrict__ partials, int n) {
  __shared__ int s[1024];
  int t = threadIdx.x;
  int idx = blockIdx.x * 1024 + t;
  int v = (idx < n) ? cnt[idx] : 0;
  s[t] = v;
  __syncthreads();
  for (int d = 1; d < 1024; d <<= 1) {
    int tmp = (t >= d) ? s[t - d] : 0;
    __syncthreads();
    s[t] += tmp;
    __syncthreads();
  }
  if (idx < n) off[idx] = s[t] - v;
  if (t == 1023) partials[blockIdx.x] = s[1023];
}

// ---------- 2b: scan chunk totals ----------
__global__ void k_scan2(const int* __restrict__ partials, int* __restrict__ pref,
                        int* __restrict__ off, int nb, int npos) {
  __shared__ int s[128];
  int t = threadIdx.x;
  int v = (t < nb) ? partials[t] : 0;
  s[t] = v;
  __syncthreads();
  for (int d = 1; d < 128; d <<= 1) {
    int tmp = (t >= d) ? s[t - d] : 0;
    __syncthreads();
    s[t] += tmp;
    __syncthreads();
  }
  if (t < nb) pref[t] = s[t] - v;
  if (t == 127) off[npos] = s[127];
}

// ---------- 2c: apply chunk prefixes ----------
__global__ void k_scan3(int* __restrict__ off, const int* __restrict__ pref,
                        int* __restrict__ cursor, int n) {
  int i = blockIdx.x * 256 + threadIdx.x;
  if (i < n) {
    int o = off[i] + pref[i >> 10];
    off[i] = o;
    cursor[i] = o;
  }
}

// ---------- 3: bucket fill (m = -norm, packed float4) ----------
__global__ void k_fill(const int* __restrict__ ei,
                       const void* nr, const void* ni, const void* nj, const void* nk,
                       const int* __restrict__ flagp, int* __restrict__ cursor,
                       int* __restrict__ srcS, float4* __restrict__ m4, int ne) {
  int isbf = *flagp;
  int e = blockIdx.x * 256 + threadIdx.x;
  if (e >= ne) return;
  int s = ei[e];
  int d = ei[ne + e];
  int pos = atomicAdd(&cursor[d], 1);
  srcS[pos] = s;
  float4 m;
  m.x = -ldf(nr, e, isbf);
  m.y = -ldf(ni, e, isbf);
  m.z = -ldf(nj, e, isbf);
  m.w = -ldf(nk, e, isbf);
  m4[pos] = m;
}

// ---------- 3b: interleave inputs -> Xg[node][feat][comp] bf16 ----------
__global__ __launch_bounds__(256) void k_ilv(
    const void* X0, const void* X1, const void* X2, const void* X3,
    const int* __restrict__ flagp, unsigned short* __restrict__ Xg, int n) {
  int isbf = *flagp;
  int lane = threadIdx.x & 63;
  int node = blockIdx.x * 4 + (threadIdx.x >> 6);
  if (node >= n) return;
  int idx = node * 64 + lane;
  unsigned int lo = f2b(ldf(X0, idx, isbf)) | ((unsigned int)f2b(ldf(X1, idx, isbf)) << 16);
  unsigned int hi = f2b(ldf(X2, idx, isbf)) | ((unsigned int)f2b(ldf(X3, idx, isbf)) << 16);
  uint2 g = make_uint2(lo, hi);
  *(uint2*)(Xg + (size_t)node * 256 + lane * 4) = g;
}

// ---------- 4: quaternion aggregation (wave per node, bf16 interleaved gather) ----------
// writes T[node][k] bf16 row-major, k = c*64 + feat
__global__ __launch_bounds__(256) void k_agg(
    const unsigned short* __restrict__ Xg, const int* __restrict__ off,
    const int* __restrict__ srcS, const float4* __restrict__ m4,
    unsigned short* __restrict__ T, int nnodes) {
  int lane = threadIdx.x & 63;
  int node = blockIdx.x * 4 + (threadIdx.x >> 6);
  if (node >= nnodes) return;
  int rs = off[node], re = off[node + 1];
  float tr = 0.f, ti = 0.f, tj = 0.f, tk = 0.f;
  for (int e = rs; e < re; ++e) {
    int s = srcS[e];
    float4 m = m4[e];
    uint2 g = *(const uint2*)(Xg + (size_t)s * 256 + lane * 4);
    float xr = b2f(g.x & 0xffffu);
    float xi = b2f(g.x >> 16);
    float xj = b2f(g.y & 0xffffu);
    float xk = b2f(g.y >> 16);
    tr += m.x * xr - m.y * xi - m.z * xj - m.w * xk;
    ti += m.x * xi + m.y * xr + m.z * xk - m.w * xj;
    tj += m.x * xj - m.y * xk + m.z * xr + m.w * xi;
    tk += m.x * xk + m.y * xj - m.z * xi + m.w * xr;
  }
  size_t o = (size_t)node * 256 + lane;
  T[o] = f2b(tr);
  T[o + 64] = f2b(ti);
  T[o + 128] = f2b(tj);
  T[o + 192] = f2b(tk);
}

// ---------- 5: build Weff^T (K-major, bf16) + bias ----------
// Weff_t[col*256 + krow] = sign(a,c) * W[a^c][kk][h]; a=krow>>6,kk=krow&63,c=col>>6,h=col&63
__global__ void k_weff(const void* W, const void* b, const int* __restrict__ flagp,
                       unsigned short* __restrict__ Wt, float* __restrict__ bcat) {
  int isbf = *flagp;
  int t = blockIdx.x * 256 + threadIdx.x;  // 0..65535
  int col = t >> 8;
  int krow = t & 255;
  int a = krow >> 6, kk = krow & 63, c = col >> 6, h = col & 63;
  int w = a ^ c;
  float sgn = ((0x3950 >> (a * 4 + c)) & 1) ? -1.f : 1.f;
  Wt[t] = f2b(sgn * ldf(W, w * 4096 + kk * 64 + h, isbf));
  if (t < 256) bcat[t] = ldf(b, t, isbf);
}

// ---------- 6: MFMA GEMM  C = T(Mx256) @ Weff(256x256) + bias, relu ----------
// block=256 (4 waves), wave tile 64x64 (4x4 16x16x32 frags), no LDS.
// mode 0: write relu'd C as interleaved bf16 Xg[node*256 + f*4 + c]
// mode 1: fused readout: P[node*4 + e + 2d] += relu(C)[node][col] * Cw[d][c*128+e*64+f]
__global__ __launch_bounds__(256) void k_gemm(
    const unsigned short* __restrict__ A, const unsigned short* __restrict__ Bw,
    const float* __restrict__ bias, int M, int mode,
    unsigned short* __restrict__ XgOut,
    float* __restrict__ P, const void* Cw, const int* __restrict__ flagp) {
  int t = threadIdx.x;
  int lane = t & 63;
  int wx = t >> 6;               // 0..3 -> n quadrant
  int l15 = lane & 15, quad = lane >> 4;
  int m0 = blockIdx.x * 64;
  int n0 = wx * 64;

  f32x4 acc[4][4];
#pragma unroll
  for (int mi = 0; mi < 4; mi++)
#pragma unroll
    for (int ni = 0; ni < 4; ni++) acc[mi][ni] = (f32x4){0.f, 0.f, 0.f, 0.f};

  const unsigned short* Ab = A + (size_t)(m0 + l15) * 256 + quad * 8;
  const unsigned short* Bb = Bw + (size_t)(n0 + l15) * 256 + quad * 8;

#pragma unroll
  for (int k0 = 0; k0 < 256; k0 += 32) {
    short8 av[4], bv[4];
#pragma unroll
    for (int mi = 0; mi < 4; mi++) av[mi] = *(const short8*)(Ab + mi * 16 * 256 + k0);
#pragma unroll
    for (int ni = 0; ni < 4; ni++) bv[ni] = *(const short8*)(Bb + ni * 16 * 256 + k0);
#pragma unroll
    for (int mi = 0; mi < 4; mi++)
#pragma unroll
      for (int ni = 0; ni < 4; ni++)
        acc[mi][ni] = __builtin_amdgcn_mfma_f32_16x16x32_bf16(av[mi], bv[ni], acc[mi][ni], 0, 0, 0);
  }

  float bias_v[4];
#pragma unroll
  for (int ni = 0; ni < 4; ni++) bias_v[ni] = bias[n0 + ni * 16 + l15];

  if (mode == 0) {
    // interleaved bf16 store
#pragma unroll
    for (int mi = 0; mi < 4; mi++) {
      int nodeb = m0 + mi * 16 + quad * 4;
#pragma unroll
      for (int ni = 0; ni < 4; ni++) {
        int col = n0 + ni * 16 + l15;
        int c = col >> 6, f = col & 63;
#pragma unroll
        for (int r = 0; r < 4; r++) {
          int node = nodeb + r;
          if (node < M) {
            float v = fmaxf(acc[mi][ni][r] + bias_v[ni], 0.f);
            XgOut[(size_t)node * 256 + f * 4 + c] = f2b(v);
          }
        }
      }
    }
  } else {
    int isbf = *flagp;
    float cw[4][4];
#pragma unroll
    for (int ni = 0; ni < 4; ni++) {
      int col = n0 + ni * 16 + l15;
      int c = col >> 6, f = col & 63;
#pragma unroll
      for (int d = 0; d < 2; d++)
#pragma unroll
        for (int e = 0; e < 2; e++)
          cw[ni][e + 2 * d] = ldf(Cw, d * 512 + c * 128 + e * 64 + f, isbf);
    }
#pragma unroll
    for (int mi = 0; mi < 4; mi++) {
      int nodeb = m0 + mi * 16 + quad * 4;
#pragma unroll
      for (int r = 0; r < 4; r++) {
        int node = nodeb + r;
        float pd0 = 0.f, pd1 = 0.f, pd2 = 0.f, pd3 = 0.f;
#pragma unroll
        for (int ni = 0; ni < 4; ni++) {
          float v = fmaxf(acc[mi][ni][r] + bias_v[ni], 0.f);
          pd0 += v * cw[ni][0];
          pd1 += v * cw[ni][1];
          pd2 += v * cw[ni][2];
          pd3 += v * cw[ni][3];
        }
#pragma unroll
        for (int o = 1; o < 16; o <<= 1) {
          pd0 += __shfl_xor(pd0, o);
          pd1 += __shfl_xor(pd1, o);
          pd2 += __shfl_xor(pd2, o);
          pd3 += __shfl_xor(pd3, o);
        }
        if (l15 == 0 && node < M) {
          atomicAdd(&P[node * 4 + 0], pd0);
          atomicAdd(&P[node * 4 + 1], pd1);
          atomicAdd(&P[node * 4 + 2], pd2);
          atomicAdd(&P[node * 4 + 3], pd3);
        }
      }
    }
  }
}

// ---------- 8: per-query logits + log_softmax ----------
__global__ void k_query(const int* __restrict__ qe, const float* __restrict__ P,
                        const void* Cb, const int* __restrict__ flagp,
                        void* out, int nq) {
  int isbf = *flagp;
  int q = blockIdx.x * 256 + threadIdx.x;
  if (q >= nq) return;
  int q0 = qe[q * 2], q1 = qe[q * 2 + 1];
  float l0 = P[q0 * 4 + 0] + P[q1 * 4 + 1] + ldf(Cb, 0, isbf);
  float l1 = P[q0 * 4 + 2] + P[q1 * 4 + 3] + ldf(Cb, 1, isbf);
  float m = fmaxf(l0, l1);
  float lse = m + logf(expf(l0 - m) + expf(l1 - m));
  float o0 = l0 - lse, o1 = l1 - lse;
  if (isbf) {
    __hip_bfloat16* o = (__hip_bfloat16*)out;
    o[q * 2] = __float2bfloat16(o0);
    o[q * 2 + 1] = __float2bfloat16(o1);
  } else {
    float* o = (float*)out;
    o[q * 2] = o0;
    o[q * 2 + 1] = o1;
  }
}

extern "C" void kernel_launch(void* const* d_in, const int* in_sizes, int n_in,
                              void* d_out, int out_size, void* d_ws, size_t ws_size,
                              hipStream_t stream) {
  const int N = N_NODESC, NE = N_EDGESC, NQ = N_QUERYC;
  const int NPAD = N + 64;  // GEMM reads up to 63 rows past M

  char* w = (char*)d_ws;
  auto alloc = [&](size_t bytes) -> void* {
    void* p = (void*)w;
    w += (bytes + 255) & ~(size_t)255;
    return p;
  };
  int* flag       = (int*)alloc(4);
  int* offsets    = (int*)alloc((size_t)(N + 1) * 4);
  int* cursor     = (int*)alloc((size_t)N * 4);
  int* partials   = (int*)alloc(128 * 4);
  int* pref       = (int*)alloc(128 * 4);
  int* srcS       = (int*)alloc((size_t)NE * 4);
  float4* m4      = (float4*)alloc((size_t)NE * 16);
  unsigned short* Tbuf = (unsigned short*)alloc((size_t)NPAD * 256 * 2);
  unsigned short* Xg   = (unsigned short*)alloc((size_t)NPAD * 256 * 2);
  unsigned short* Wt   = (unsigned short*)alloc(256 * 256 * 2);
  float* bcat     = (float*)alloc(256 * 4);
  float* P        = (float*)alloc((size_t)N * 4 * 4);
  (void)ws_size; (void)n_in; (void)in_sizes; (void)out_size;

  const int* ei = (const int*)d_in[8];

  k_sniff<<<1, 256, 0, stream>>>(d_in[0], flag);

  // CSR build
  hipMemsetAsync(cursor, 0, (size_t)N * 4, stream);
  hipMemsetAsync(P, 0, (size_t)N * 16, stream);
  k_hist<<<(NE + 255) / 256, 256, 0, stream>>>(ei + NE, cursor, NE);
  k_scan1<<<(N + 1023) / 1024, 1024, 0, stream>>>(cursor, offsets, partials, N);
  k_scan2<<<1, 128, 0, stream>>>(partials, pref, offsets, (N + 1023) / 1024, N);
  k_scan3<<<(N + 255) / 256, 256, 0, stream>>>(offsets, pref, cursor, N);
  k_fill<<<(NE + 255) / 256, 256, 0, stream>>>(ei, d_in[4], d_in[5], d_in[6], d_in[7],
                                               flag, cursor, srcS, m4, NE);

  // layer-1 gather source
  k_ilv<<<(N + 3) / 4, 256, 0, stream>>>(d_in[0], d_in[1], d_in[2], d_in[3], flag, Xg, N);

  int ggrid = (N + 63) / 64;

  // layer 1
  k_agg<<<(N + 3) / 4, 256, 0, stream>>>(Xg, offsets, srcS, m4, Tbuf, N);
  k_weff<<<256, 256, 0, stream>>>(d_in[10], d_in[11], flag, Wt, bcat);
  k_gemm<<<ggrid, 256, 0, stream>>>(Tbuf, Wt, bcat, N, 0, Xg, nullptr, nullptr, flag);

  // layer 2 (+fused readout partial dots)
  k_agg<<<(N + 3) / 4, 256, 0, stream>>>(Xg, offsets, srcS, m4, Tbuf, N);
  k_weff<<<256, 256, 0, stream>>>(d_in[12], d_in[13], flag, Wt, bcat);
  k_gemm<<<ggrid, 256, 0, stream>>>(Tbuf, Wt, bcat, N, 1, nullptr, P, d_in[14], flag);

  // queries
  k_query<<<(NQ + 255) / 256, 256, 0, stream>>>((const int*)d_in[9], P, d_in[15],
                                                flag, d_out, NQ);
}

// Round 3
// 637.402 us; speedup vs baseline: 1.6720x; 1.2376x over previous
//
#include <hip/hip_runtime.h>
#include <hip/hip_bf16.h>

#define N_NODESC 100000
#define N_EDGESC 1000000
#define N_QUERYC 100000

typedef short short8 __attribute__((ext_vector_type(8)));
typedef float f32x4 __attribute__((ext_vector_type(4)));

// ---------- dual-dtype load helper (flag: 1 = inputs are bf16, 0 = f32) ----------
__device__ __forceinline__ float ldf(const void* p, int i, int isbf) {
  return isbf ? __bfloat162float(((const __hip_bfloat16*)p)[i])
              : ((const float*)p)[i];
}
__device__ __forceinline__ unsigned short f2b(float x) {
  __hip_bfloat16 h = __float2bfloat16(x);
  return *(unsigned short*)&h;
}
__device__ __forceinline__ float b2f(unsigned int u) {
  return __uint_as_float(u << 16);
}
__device__ __forceinline__ void gload16(const void* g, void* l) {
  __builtin_amdgcn_global_load_lds(
      (const __attribute__((address_space(1))) void*)g,
      (__attribute__((address_space(3))) void*)l, 16, 0, 0);
}

// ---------- 0: sniff input dtype ----------
__global__ void k_sniff(const void* x, int* flag) {
  __shared__ int cnt;
  int t = threadIdx.x;
  if (t == 0) cnt = 0;
  __syncthreads();
  const unsigned short* h = (const unsigned short*)x;
  int local = 0;
  for (int i = t; i < 4096; i += 256) {
    int e = (h[i] >> 7) & 0xFF;
    if (e >= 107 && e <= 133) local++;
  }
  atomicAdd(&cnt, local);
  __syncthreads();
  if (t == 0) *flag = (cnt >= 3482) ? 1 : 0;
}

// ---------- 1: histogram of dst ----------
__global__ void k_hist(const int* __restrict__ dst, int* __restrict__ cnt, int ne) {
  int e = blockIdx.x * 256 + threadIdx.x;
  if (e < ne) atomicAdd(&cnt[dst[e]], 1);
}

// ---------- 2a: per-chunk exclusive scan ----------
__global__ void k_scan1(const int* __restrict__ cnt, int* __restrict__ off,
                        int* __restrict__ partials, int n) {
  __shared__ int s[1024];
  int t = threadIdx.x;
  int idx = blockIdx.x * 1024 + t;
  int v = (idx < n) ? cnt[idx] : 0;
  s[t] = v;
  __syncthreads();
  for (int d = 1; d < 1024; d <<= 1) {
    int tmp = (t >= d) ? s[t - d] : 0;
    __syncthreads();
    s[t] += tmp;
    __syncthreads();
  }
  if (idx < n) off[idx] = s[t] - v;
  if (t == 1023) partials[blockIdx.x] = s[1023];
}

// ---------- 2b: scan chunk totals ----------
__global__ void k_scan2(const int* __restrict__ partials, int* __restrict__ pref,
                        int* __restrict__ off, int nb, int npos) {
  __shared__ int s[128];
  int t = threadIdx.x;
  int v = (t < nb) ? partials[t] : 0;
  s[t] = v;
  __syncthreads();
  for (int d = 1; d < 128; d <<= 1) {
    int tmp = (t >= d) ? s[t - d] : 0;
    __syncthreads();
    s[t] += tmp;
    __syncthreads();
  }
  if (t < nb) pref[t] = s[t] - v;
  if (t == 127) off[npos] = s[127];
}

// ---------- 2c: apply chunk prefixes ----------
__global__ void k_scan3(int* __restrict__ off, const int* __restrict__ pref,
                        int* __restrict__ cursor, int n) {
  int i = blockIdx.x * 256 + threadIdx.x;
  if (i < n) {
    int o = off[i] + pref[i >> 10];
    off[i] = o;
    cursor[i] = o;
  }
}

// ---------- 3: bucket fill (m = -norm, packed float4) ----------
__global__ void k_fill(const int* __restrict__ ei,
                       const void* nr, const void* ni, const void* nj, const void* nk,
                       const int* __restrict__ flagp, int* __restrict__ cursor,
                       int* __restrict__ srcS, float4* __restrict__ m4, int ne) {
  int isbf = *flagp;
  int e = blockIdx.x * 256 + threadIdx.x;
  if (e >= ne) return;
  int s = ei[e];
  int d = ei[ne + e];
  int pos = atomicAdd(&cursor[d], 1);
  srcS[pos] = s;
  float4 m;
  m.x = -ldf(nr, e, isbf);
  m.y = -ldf(ni, e, isbf);
  m.z = -ldf(nj, e, isbf);
  m.w = -ldf(nk, e, isbf);
  m4[pos] = m;
}

// ---------- 3b: interleave inputs -> Xg[node][feat][comp] bf16 ----------
__global__ __launch_bounds__(256) void k_ilv(
    const void* X0, const void* X1, const void* X2, const void* X3,
    const int* __restrict__ flagp, unsigned short* __restrict__ Xg, int n) {
  int isbf = *flagp;
  int lane = threadIdx.x & 63;
  int node = blockIdx.x * 4 + (threadIdx.x >> 6);
  if (node >= n) return;
  int idx = node * 64 + lane;
  unsigned int lo = f2b(ldf(X0, idx, isbf)) | ((unsigned int)f2b(ldf(X1, idx, isbf)) << 16);
  unsigned int hi = f2b(ldf(X2, idx, isbf)) | ((unsigned int)f2b(ldf(X3, idx, isbf)) << 16);
  uint2 g = make_uint2(lo, hi);
  *(uint2*)(Xg + (size_t)node * 256 + lane * 4) = g;
}

// ---------- 4: quaternion aggregation (wave per node, bf16 interleaved gather) ----------
__global__ __launch_bounds__(256) void k_agg(
    const unsigned short* __restrict__ Xg, const int* __restrict__ off,
    const int* __restrict__ srcS, const float4* __restrict__ m4,
    unsigned short* __restrict__ T, int nnodes) {
  int lane = threadIdx.x & 63;
  int node = blockIdx.x * 4 + (threadIdx.x >> 6);
  if (node >= nnodes) return;
  int rs = off[node], re = off[node + 1];
  float tr = 0.f, ti = 0.f, tj = 0.f, tk = 0.f;
  int e = rs;
  for (; e + 1 < re; e += 2) {
    int s0 = srcS[e], s1 = srcS[e + 1];
    float4 ma = m4[e], mb = m4[e + 1];
    uint2 g0 = *(const uint2*)(Xg + (size_t)s0 * 256 + lane * 4);
    uint2 g1 = *(const uint2*)(Xg + (size_t)s1 * 256 + lane * 4);
    {
      float xr = b2f(g0.x & 0xffffu), xi = b2f(g0.x >> 16);
      float xj = b2f(g0.y & 0xffffu), xk = b2f(g0.y >> 16);
      tr += ma.x * xr - ma.y * xi - ma.z * xj - ma.w * xk;
      ti += ma.x * xi + ma.y * xr + ma.z * xk - ma.w * xj;
      tj += ma.x * xj - ma.y * xk + ma.z * xr + ma.w * xi;
      tk += ma.x * xk + ma.y * xj - ma.z * xi + ma.w * xr;
    }
    {
      float xr = b2f(g1.x & 0xffffu), xi = b2f(g1.x >> 16);
      float xj = b2f(g1.y & 0xffffu), xk = b2f(g1.y >> 16);
      tr += mb.x * xr - mb.y * xi - mb.z * xj - mb.w * xk;
      ti += mb.x * xi + mb.y * xr + mb.z * xk - mb.w * xj;
      tj += mb.x * xj - mb.y * xk + mb.z * xr + mb.w * xi;
      tk += mb.x * xk + mb.y * xj - mb.z * xi + mb.w * xr;
    }
  }
  if (e < re) {
    int s0 = srcS[e];
    float4 ma = m4[e];
    uint2 g0 = *(const uint2*)(Xg + (size_t)s0 * 256 + lane * 4);
    float xr = b2f(g0.x & 0xffffu), xi = b2f(g0.x >> 16);
    float xj = b2f(g0.y & 0xffffu), xk = b2f(g0.y >> 16);
    tr += ma.x * xr - ma.y * xi - ma.z * xj - ma.w * xk;
    ti += ma.x * xi + ma.y * xr + ma.z * xk - ma.w * xj;
    tj += ma.x * xj - ma.y * xk + ma.z * xr + ma.w * xi;
    tk += ma.x * xk + ma.y * xj - ma.z * xi + ma.w * xr;
  }
  size_t o = (size_t)node * 256 + lane;
  T[o] = f2b(tr);
  T[o + 64] = f2b(ti);
  T[o + 128] = f2b(tj);
  T[o + 192] = f2b(tk);
}

// ---------- 5: build Weff^T (K-major, bf16) + bias ----------
// Wt[col*256 + krow] = sign(a,c) * W[a^c][kk][h]; a=krow>>6,kk=krow&63,c=col>>6,h=col&63
__global__ void k_weff(const void* W, const void* b, const int* __restrict__ flagp,
                       unsigned short* __restrict__ Wt, float* __restrict__ bcat) {
  int isbf = *flagp;
  int t = blockIdx.x * 256 + threadIdx.x;
  int col = t >> 8;
  int krow = t & 255;
  int a = krow >> 6, kk = krow & 63, c = col >> 6, h = col & 63;
  int w = a ^ c;
  float sgn = ((0x3950 >> (a * 4 + c)) & 1) ? -1.f : 1.f;
  Wt[t] = f2b(sgn * ldf(W, w * 4096 + kk * 64 + h, isbf));
  if (t < 256) bcat[t] = ldf(b, t, isbf);
}

// ---------- 6: LDS-staged MFMA GEMM  C = A(Mx256) @ Weff(256x256) + bias, relu ----------
// grid (ceil(M/128), 2); block 256 (4 waves). blockIdx.y = y tiles f in [y*32,y*32+32).
// Block covers 128 rows x 128 cols where cols = { c*64 + y*32 + fu : c<4, fu<32 }.
// Wave w: rows (w>>1)*64..+64, f-sub (w&1)*16 + l15; its 4 ni frags are the 4 components c.
// mode 0: packed interleaved bf16 store Xg[node*256 + f*4 + c] (8B/lane, coalesced)
// mode 1: fused readout into P[node*4 + e + 2d]
__global__ __launch_bounds__(256) void k_gemm(
    const unsigned short* __restrict__ A, const unsigned short* __restrict__ Bw,
    const float* __restrict__ bias, int M, int mode,
    unsigned short* __restrict__ XgOut,
    float* __restrict__ P, const void* Cw, const int* __restrict__ flagp) {
  __shared__ unsigned short Asm[128 * 64];  // [rowt][slot] 16KB, slot=8 shorts, XOR-swizzled
  __shared__ unsigned short Bsm[128 * 64];  // [ct][slot]   16KB

  int t = threadIdx.x;
  int lane = t & 63;
  int w = t >> 6;
  int l15 = lane & 15, quad = lane >> 4;
  int m0 = blockIdx.x * 128;
  int y = blockIdx.y;

  // staging indices for this lane (chunk granularity = 16B = 8 shorts)
  // chk = (w*4+j)*64 + lane ; row/ct = chk>>3 ; kbL = chk&7 ; kbG = kbL ^ swz(row)
  int chk0 = w * 256 + lane;  // j=0 chunk index
  f32x4 acc[4][4];
#pragma unroll
  for (int mi = 0; mi < 4; mi++)
#pragma unroll
    for (int c = 0; c < 4; c++) acc[mi][c] = (f32x4){0.f, 0.f, 0.f, 0.f};

  const char* Ag = (const char*)A;
  const char* Bg = (const char*)Bw;

  for (int k0 = 0; k0 < 256; k0 += 64) {
    if (k0) __syncthreads();
    // stage A: 128 rows x 64 k  (4 chunks per wave)
#pragma unroll
    for (int j = 0; j < 4; j++) {
      int chk = chk0 + j * 64;
      int rowt = chk >> 3, kbL = chk & 7;
      int kbG = kbL ^ ((rowt ^ (rowt >> 3)) & 7);
      gload16(Ag + ((size_t)(m0 + rowt) * 512 + (size_t)k0 * 2 + kbG * 16),
              (char*)Asm + (w * 4 + j) * 1024);
    }
    // stage B: 128 cols x 64 k; ct = c*32 + fu, col = c*64 + y*32 + fu
#pragma unroll
    for (int j = 0; j < 4; j++) {
      int chk = chk0 + j * 64;
      int ct = chk >> 3, kbL = chk & 7;
      int kbG = kbL ^ ((ct ^ (ct >> 3)) & 7);
      int col = (ct >> 5) * 64 + y * 32 + (ct & 31);
      gload16(Bg + ((size_t)col * 512 + (size_t)k0 * 2 + kbG * 16),
              (char*)Bsm + (w * 4 + j) * 1024);
    }
    __syncthreads();
#pragma unroll
    for (int ks = 0; ks < 2; ks++) {
      short8 av[4], bv[4];
#pragma unroll
      for (int mi = 0; mi < 4; mi++) {
        int rowt = (w >> 1) * 64 + mi * 16 + l15;
        int slot = (ks * 4 + quad) ^ ((rowt ^ (rowt >> 3)) & 7);
        av[mi] = *(const short8*)&Asm[rowt * 64 + slot * 8];
      }
#pragma unroll
      for (int c = 0; c < 4; c++) {
        int ct = c * 32 + (w & 1) * 16 + l15;
        int slot = (ks * 4 + quad) ^ ((ct ^ (ct >> 3)) & 7);
        bv[c] = *(const short8*)&Bsm[ct * 64 + slot * 8];
      }
#pragma unroll
      for (int mi = 0; mi < 4; mi++)
#pragma unroll
        for (int c = 0; c < 4; c++)
          acc[mi][c] = __builtin_amdgcn_mfma_f32_16x16x32_bf16(av[mi], bv[c], acc[mi][c], 0, 0, 0);
    }
  }

  int fl = y * 32 + (w & 1) * 16 + l15;  // f for this lane
  float bias_v[4];
#pragma unroll
  for (int c = 0; c < 4; c++) bias_v[c] = bias[c * 64 + fl];

  if (mode == 0) {
#pragma unroll
    for (int mi = 0; mi < 4; mi++) {
#pragma unroll
      for (int r = 0; r < 4; r++) {
        int node = m0 + (w >> 1) * 64 + mi * 16 + quad * 4 + r;
        unsigned int lo = f2b(fmaxf(acc[mi][0][r] + bias_v[0], 0.f)) |
                          ((unsigned int)f2b(fmaxf(acc[mi][1][r] + bias_v[1], 0.f)) << 16);
        unsigned int hi = f2b(fmaxf(acc[mi][2][r] + bias_v[2], 0.f)) |
                          ((unsigned int)f2b(fmaxf(acc[mi][3][r] + bias_v[3], 0.f)) << 16);
        *(uint2*)(XgOut + (size_t)node * 256 + fl * 4) = make_uint2(lo, hi);
      }
    }
  } else {
    int isbf = *flagp;
    float cw[4][4];
#pragma unroll
    for (int c = 0; c < 4; c++)
#pragma unroll
      for (int d = 0; d < 2; d++)
#pragma unroll
        for (int e = 0; e < 2; e++)
          cw[c][e + 2 * d] = ldf(Cw, d * 512 + c * 128 + e * 64 + fl, isbf);
#pragma unroll
    for (int mi = 0; mi < 4; mi++) {
#pragma unroll
      for (int r = 0; r < 4; r++) {
        int node = m0 + (w >> 1) * 64 + mi * 16 + quad * 4 + r;
        float pd0 = 0.f, pd1 = 0.f, pd2 = 0.f, pd3 = 0.f;
#pragma unroll
        for (int c = 0; c < 4; c++) {
          float v = fmaxf(acc[mi][c][r] + bias_v[c], 0.f);
          pd0 += v * cw[c][0];
          pd1 += v * cw[c][1];
          pd2 += v * cw[c][2];
          pd3 += v * cw[c][3];
        }
#pragma unroll
        for (int o = 1; o < 16; o <<= 1) {
          pd0 += __shfl_xor(pd0, o);
          pd1 += __shfl_xor(pd1, o);
          pd2 += __shfl_xor(pd2, o);
          pd3 += __shfl_xor(pd3, o);
        }
        if (l15 == 0 && node < M) {
          atomicAdd(&P[node * 4 + 0], pd0);
          atomicAdd(&P[node * 4 + 1], pd1);
          atomicAdd(&P[node * 4 + 2], pd2);
          atomicAdd(&P[node * 4 + 3], pd3);
        }
      }
    }
  }
}

// ---------- 8: per-query logits + log_softmax ----------
__global__ void k_query(const int* __restrict__ qe, const float* __restrict__ P,
                        const void* Cb, const int* __restrict__ flagp,
                        void* out, int nq) {
  int isbf = *flagp;
  int q = blockIdx.x * 256 + threadIdx.x;
  if (q >= nq) return;
  int q0 = qe[q * 2], q1 = qe[q * 2 + 1];
  float l0 = P[q0 * 4 + 0] + P[q1 * 4 + 1] + ldf(Cb, 0, isbf);
  float l1 = P[q0 * 4 + 2] + P[q1 * 4 + 3] + ldf(Cb, 1, isbf);
  float m = fmaxf(l0, l1);
  float lse = m + logf(expf(l0 - m) + expf(l1 - m));
  float o0 = l0 - lse, o1 = l1 - lse;
  if (isbf) {
    __hip_bfloat16* o = (__hip_bfloat16*)out;
    o[q * 2] = __float2bfloat16(o0);
    o[q * 2 + 1] = __float2bfloat16(o1);
  } else {
    float* o = (float*)out;
    o[q * 2] = o0;
    o[q * 2 + 1] = o1;
  }
}

extern "C" void kernel_launch(void* const* d_in, const int* in_sizes, int n_in,
                              void* d_out, int out_size, void* d_ws, size_t ws_size,
                              hipStream_t stream) {
  const int N = N_NODESC, NE = N_EDGESC, NQ = N_QUERYC;
  const int NPAD = 100224;  // >= 782*128 = 100096 (GEMM stages full 128-row tiles)

  char* w = (char*)d_ws;
  auto alloc = [&](size_t bytes) -> void* {
    void* p = (void*)w;
    w += (bytes + 255) & ~(size_t)255;
    return p;
  };
  int* flag       = (int*)alloc(4);
  int* offsets    = (int*)alloc((size_t)(N + 1) * 4);
  int* cursor     = (int*)alloc((size_t)N * 4);
  int* partials   = (int*)alloc(128 * 4);
  int* pref       = (int*)alloc(128 * 4);
  int* srcS       = (int*)alloc((size_t)NE * 4);
  float4* m4      = (float4*)alloc((size_t)NE * 16);
  unsigned short* Tbuf = (unsigned short*)alloc((size_t)NPAD * 256 * 2);
  unsigned short* Xg   = (unsigned short*)alloc((size_t)NPAD * 256 * 2);
  unsigned short* Wt   = (unsigned short*)alloc(256 * 256 * 2);
  float* bcat     = (float*)alloc(256 * 4);
  float* P        = (float*)alloc((size_t)N * 4 * 4);
  (void)ws_size; (void)n_in; (void)in_sizes; (void)out_size;

  const int* ei = (const int*)d_in[8];

  k_sniff<<<1, 256, 0, stream>>>(d_in[0], flag);

  // CSR build
  hipMemsetAsync(cursor, 0, (size_t)N * 4, stream);
  hipMemsetAsync(P, 0, (size_t)N * 16, stream);
  k_hist<<<(NE + 255) / 256, 256, 0, stream>>>(ei + NE, cursor, NE);
  k_scan1<<<(N + 1023) / 1024, 1024, 0, stream>>>(cursor, offsets, partials, N);
  k_scan2<<<1, 128, 0, stream>>>(partials, pref, offsets, (N + 1023) / 1024, N);
  k_scan3<<<(N + 255) / 256, 256, 0, stream>>>(offsets, pref, cursor, N);
  k_fill<<<(NE + 255) / 256, 256, 0, stream>>>(ei, d_in[4], d_in[5], d_in[6], d_in[7],
                                               flag, cursor, srcS, m4, NE);

  // layer-1 gather source
  k_ilv<<<(N + 3) / 4, 256, 0, stream>>>(d_in[0], d_in[1], d_in[2], d_in[3], flag, Xg, N);

  dim3 ggrid((N + 127) / 128, 2);

  // layer 1
  k_agg<<<(N + 3) / 4, 256, 0, stream>>>(Xg, offsets, srcS, m4, Tbuf, N);
  k_weff<<<256, 256, 0, stream>>>(d_in[10], d_in[11], flag, Wt, bcat);
  k_gemm<<<ggrid, 256, 0, stream>>>(Tbuf, Wt, bcat, N, 0, Xg, nullptr, nullptr, flag);

  // layer 2 (+fused readout partial dots)
  k_agg<<<(N + 3) / 4, 256, 0, stream>>>(Xg, offsets, srcS, m4, Tbuf, N);
  k_weff<<<256, 256, 0, stream>>>(d_in[12], d_in[13], flag, Wt, bcat);
  k_gemm<<<ggrid, 256, 0, stream>>>(Tbuf, Wt, bcat, N, 1, nullptr, P, d_in[14], flag);

  // queries
  k_query<<<(NQ + 255) / 256, 256, 0, stream>>>((const int*)d_in[9], P, d_in[15],
                                                flag, d_out, NQ);
}